// Round 2
// baseline (265.448 us; speedup 1.0000x reference)
//
#include <hip/hip_runtime.h>
#include <hip/hip_bf16.h>

typedef __attribute__((ext_vector_type(8))) __bf16 bf16x8;
typedef __attribute__((ext_vector_type(8))) short short8;
typedef __attribute__((ext_vector_type(4))) float f32x4;
typedef __attribute__((ext_vector_type(2))) unsigned int uint2v;

#define KSTRIDE 72
#define LOG2E 1.44269504088896340736f

// pack two fp32 -> two bf16 (lo in low short), round-half-up: +0x8000 then take hi16
__device__ __forceinline__ unsigned pack2bf(float lo, float hi) {
    unsigned a = __builtin_bit_cast(unsigned, lo) + 0x8000u;
    unsigned b = __builtin_bit_cast(unsigned, hi) + 0x8000u;
    return __builtin_amdgcn_perm(b, a, 0x07060302u);  // D = [a.b2,a.b3,b.b2,b.b3]
}

__device__ __forceinline__ bf16x8 ldfrag(const short* p) {
    short8 s = *reinterpret_cast<const short8*>(p);
    return __builtin_bit_cast(bf16x8, s);
}

// Geometry (module constants). Blocks ordered LONGEST-FIRST to cut the tail:
// order ss = {stage1 s0(18kt), s2(16), s1(14), s3(12), stage0 s0(10), s2(9), s1(8), s3(7)}
__global__ __launch_bounds__(256) void vfa_kernel(
    const float* __restrict__ qv, const float* __restrict__ kv, const float* __restrict__ vv,
    const float* __restrict__ eq, const float* __restrict__ ek, const float* __restrict__ ev,
    const float* __restrict__ scale_p, float* __restrict__ out)
{
    constexpr int H = 16, Dh = 64, ENC = 128, SV = 1536;
    constexpr int SS_CUM[9] = {0,288,544,768,960,1120,1264,1392,1504};
    constexpr int SEQL[8] = {1152,1008,864,720,640,560,480,400};
    constexpr int QTN[8]  = {18,16,14,12,10,9,8,7};
    constexpr int OB[8]   = {2080,4096,3232,5104,0,1120,640,1680};
    constexpr int BB[8]   = {1,5,3,7,0,4,2,6};
    constexpr int ISUM[8] = {512,512,512,512,0,0,0,0};

    __shared__ __align__(16) short kbuf[64*KSTRIDE];   // K[key][d]     bf16
    __shared__ __align__(16) short vbuf[64*KSTRIDE];   // V^T[d][key]   bf16
    __shared__ __align__(16) short pbuf[4*16*KSTRIDE]; // per-wave P[q][key] bf16

    const int bid = blockIdx.x;
    int ss = 0;
    #pragma unroll
    for (int i = 1; i < 8; ++i) ss += (bid >= SS_CUM[i]) ? 1 : 0;
    const int seqlen   = SEQL[ss];
    const int nqt      = QTN[ss];
    const int b        = BB[ss];
    const int isum     = ISUM[ss];
    const int out_base = OB[ss];
    const int local    = bid - SS_CUM[ss];
    const int head     = local / nqt;          // head-major: consecutive blocks share K/V (L2)
    const int qt       = local - head * nqt;

    const int tid  = threadIdx.x;
    const int wave = tid >> 6;
    const int lane = tid & 63;
    const int quad = lane >> 4;
    const int l15  = lane & 15;

    const float qmul = scale_p[0] * LOG2E;     // fold scale + log2(e) into Q

    // ---- Q fragments (A layout: m = lane&15, k = quad*8 + j), kept in regs ----
    const int qrow = qt*64 + wave*16 + l15;    // wave-uniform enc/video split (16 | 128)
    const float* qrp;
    if (qrow < ENC) qrp = eq + ((b*ENC + qrow)*H + head)*Dh;
    else            qrp = qv + (((b*SV + isum) + (qrow - ENC))*H + head)*Dh;
    bf16x8 qfrag[2];
    #pragma unroll
    for (int f = 0; f < 2; ++f) {
        const float* p = qrp + f*32 + quad*8;
        float4 a = *reinterpret_cast<const float4*>(p);
        float4 c = *reinterpret_cast<const float4*>(p + 4);
        unsigned u[4];
        u[0] = pack2bf(a.x*qmul, a.y*qmul);
        u[1] = pack2bf(a.z*qmul, a.w*qmul);
        u[2] = pack2bf(c.x*qmul, c.y*qmul);
        u[3] = pack2bf(c.z*qmul, c.w*qmul);
        short8 s;
        #pragma unroll
        for (int i = 0; i < 4; ++i) { s[2*i] = (short)(u[i] & 0xFFFF); s[2*i+1] = (short)(u[i] >> 16); }
        qfrag[f] = __builtin_bit_cast(bf16x8, s);
    }

    f32x4 acc[4];
    #pragma unroll
    for (int dt = 0; dt < 4; ++dt) acc[dt] = {0.f,0.f,0.f,0.f};
    float m_r[4], l_r[4];
    #pragma unroll
    for (int r = 0; r < 4; ++r) { m_r[r] = -INFINITY; l_r[r] = 0.f; }

    const int key_local = tid >> 2;                 // 0..63
    const int cb = (tid & 3) * 4;                   // 0,4,8,12
    const int nkt = (seqlen + 63) >> 6;
    const bool evenk = (key_local & 1) == 0;
    const bool evenl = (l15 & 1) == 0;

    short* pw = pbuf + wave*16*KSTRIDE;             // wave-private P region

    float4 kreg[4], vreg[4];
    auto load_tile = [&](int kt) {
        const int kr = kt*64 + key_local;           // enc/video split wave-uniform (ENC=128=2 tiles)
        const float *krow, *vrow;
        if (kr < ENC) {
            krow = ek + ((b*ENC + kr)*H + head)*Dh;
            vrow = ev + ((b*ENC + kr)*H + head)*Dh;
        } else {
            const int row = (b*SV + isum) + (kr - ENC);
            krow = kv + (row*H + head)*Dh;
            vrow = vv + (row*H + head)*Dh;
        }
        #pragma unroll
        for (int j = 0; j < 4; ++j) {
            const int d0 = cb + j*16;
            kreg[j] = *reinterpret_cast<const float4*>(krow + d0);
            vreg[j] = *reinterpret_cast<const float4*>(vrow + d0);
        }
    };

    load_tile(0);

    for (int kt = 0; kt < nkt; ++kt) {
        if (kt) __syncthreads();                    // waves done reading LDS of tile kt-1

        // ---- regs -> LDS (bf16), K row-major, V transposed with key-paired u32 writes ----
        #pragma unroll
        for (int j = 0; j < 4; ++j) {
            const int d0 = cb + j*16;
            uint2v kp2;
            kp2.x = pack2bf(kreg[j].x, kreg[j].y);
            kp2.y = pack2bf(kreg[j].z, kreg[j].w);
            *reinterpret_cast<uint2v*>(&kbuf[key_local*KSTRIDE + d0]) = kp2;
            #pragma unroll
            for (int i = 0; i < 4; ++i) {
                float mv = (i==0)?vreg[j].x:(i==1)?vreg[j].y:(i==2)?vreg[j].z:vreg[j].w;
                unsigned mu = __builtin_bit_cast(unsigned, mv) + 0x8000u;
                unsigned pu = (unsigned)__shfl_xor((int)mu, 4, 64);   // partner key (key^1)
                if (evenk)
                    *reinterpret_cast<unsigned*>(&vbuf[(d0+i)*KSTRIDE + key_local]) =
                        __builtin_amdgcn_perm(pu, mu, 0x07060302u);
            }
        }
        if (kt + 1 < nkt) load_tile(kt + 1);        // prefetch next tile (latency hidden by compute)
        __syncthreads();

        const int rem  = seqlen - kt*64;            // multiple of 16, >=16
        const int nsub = (rem >= 64) ? 4 : (rem >> 4);

        // ---- QK^T ----
        float s[4][4];
        #pragma unroll
        for (int sub = 0; sub < 4; ++sub) {
            if (sub < nsub) {
                const short* kr0 = &kbuf[(sub*16 + l15)*KSTRIDE + quad*8];
                f32x4 sv = {0.f,0.f,0.f,0.f};
                sv = __builtin_amdgcn_mfma_f32_16x16x32_bf16(qfrag[0], ldfrag(kr0),      sv, 0,0,0);
                sv = __builtin_amdgcn_mfma_f32_16x16x32_bf16(qfrag[1], ldfrag(kr0 + 32), sv, 0,0,0);
                #pragma unroll
                for (int r = 0; r < 4; ++r) s[sub][r] = sv[r];
            }
        }

        // ---- online softmax (exp2 domain) ----
        float alpha[4];
        #pragma unroll
        for (int r = 0; r < 4; ++r) {
            float mx = s[0][r];
            #pragma unroll
            for (int sub = 1; sub < 4; ++sub) if (sub < nsub) mx = fmaxf(mx, s[sub][r]);
            #pragma unroll
            for (int off = 1; off < 16; off <<= 1)
                mx = fmaxf(mx, __shfl_xor(mx, off, 64));
            const float mn = fmaxf(m_r[r], mx);
            alpha[r] = __builtin_amdgcn_exp2f(m_r[r] - mn);
            m_r[r] = mn;
        }
        #pragma unroll
        for (int dt = 0; dt < 4; ++dt)
            #pragma unroll
            for (int r = 0; r < 4; ++r) acc[dt][r] *= alpha[r];

        float rs[4] = {0.f,0.f,0.f,0.f};
        #pragma unroll
        for (int sub = 0; sub < 4; ++sub) {
            if (sub < nsub) {
                #pragma unroll
                for (int r = 0; r < 4; ++r) {
                    const float pvl = __builtin_amdgcn_exp2f(s[sub][r] - m_r[r]);
                    rs[r] += pvl;
                    unsigned mu = __builtin_bit_cast(unsigned, pvl) + 0x8000u;
                    unsigned pu = (unsigned)__shfl_xor((int)mu, 1, 64);  // partner key (l15^1)
                    if (evenl)
                        *reinterpret_cast<unsigned*>(&pw[(quad*4 + r)*KSTRIDE + sub*16 + l15]) =
                            __builtin_amdgcn_perm(pu, mu, 0x07060302u);
                }
            } else {
                #pragma unroll
                for (int r = 0; r < 4; ++r)
                    if (evenl)
                        *reinterpret_cast<unsigned*>(&pw[(quad*4 + r)*KSTRIDE + sub*16 + l15]) = 0u;
            }
        }
        #pragma unroll
        for (int r = 0; r < 4; ++r) {
            float t = rs[r];
            #pragma unroll
            for (int off = 1; off < 16; off <<= 1)
                t += __shfl_xor(t, off, 64);
            l_r[r] = l_r[r] * alpha[r] + t;
        }

        // ---- PV: O += P(16x32) x V(32x64) ----
        #pragma unroll
        for (int kstep = 0; kstep < 2; ++kstep) {
            bf16x8 pa = ldfrag(pw + l15*KSTRIDE + kstep*32 + quad*8);
            #pragma unroll
            for (int dt = 0; dt < 4; ++dt) {
                bf16x8 bv = ldfrag(&vbuf[(dt*16 + l15)*KSTRIDE + kstep*32 + quad*8]);
                acc[dt] = __builtin_amdgcn_mfma_f32_16x16x32_bf16(pa, bv, acc[dt], 0,0,0);
            }
        }
    }

    // ---- epilogue: normalize and store packed rows ----
    #pragma unroll
    for (int r = 0; r < 4; ++r) {
        const int row = qt*64 + wave*16 + quad*4 + r;
        if (row < seqlen) {
            const float inv = 1.0f / l_r[r];
            float* orow = out + ((out_base + row)*H + head)*Dh;
            #pragma unroll
            for (int dt = 0; dt < 4; ++dt)
                orow[dt*16 + l15] = acc[dt][r] * inv;
        }
    }
}

extern "C" void kernel_launch(void* const* d_in, const int* in_sizes, int n_in,
                              void* d_out, int out_size, void* d_ws, size_t ws_size,
                              hipStream_t stream) {
    const float* q     = (const float*)d_in[0];
    const float* k     = (const float*)d_in[1];
    const float* v     = (const float*)d_in[2];
    const float* eq    = (const float*)d_in[3];
    const float* ek    = (const float*)d_in[4];
    const float* ev    = (const float*)d_in[5];
    const float* scale = (const float*)d_in[11];
    float* out = (float*)d_out;

    vfa_kernel<<<dim3(1504), dim3(256), 0, stream>>>(q, k, v, eq, ek, ev, scale, out);
}

// Round 3
// 220.899 us; speedup vs baseline: 1.2017x; 1.2017x over previous
//
#include <hip/hip_runtime.h>
#include <hip/hip_bf16.h>

typedef __attribute__((ext_vector_type(8))) __bf16 bf16x8;
typedef __attribute__((ext_vector_type(8))) short short8;
typedef __attribute__((ext_vector_type(4))) float f32x4;
typedef __attribute__((ext_vector_type(4))) unsigned int uint4v;

#define KS 72
#define LOG2E 1.44269504088896340736f

// pack two fp32 -> two bf16 (lo in low short), round-half-up
__device__ __forceinline__ unsigned pack2bf(float lo, float hi) {
    unsigned a = __builtin_bit_cast(unsigned, lo) + 0x8000u;
    unsigned b = __builtin_bit_cast(unsigned, hi) + 0x8000u;
    return __builtin_amdgcn_perm(b, a, 0x07060302u);
}

__device__ __forceinline__ bf16x8 ldfrag(const short* p) {
    short8 s = *reinterpret_cast<const short8*>(p);
    return __builtin_bit_cast(bf16x8, s);
}

// S^T formulation: QK MFMA computes S^T[key][q] (A=K, B=Q); PV computes
// O^T[d][q] (A=V^T, B=P^T). Each lane owns one q row (q = lane&15) ->
// softmax reductions are 2 shuffles; P^T B-frags built via bpermute (no LDS).
__global__ __launch_bounds__(256, 6) void vfa_kernel(
    const float* __restrict__ qv, const float* __restrict__ kv, const float* __restrict__ vv,
    const float* __restrict__ eq, const float* __restrict__ ek, const float* __restrict__ ev,
    const float* __restrict__ scale_p, float* __restrict__ out)
{
    constexpr int H = 16, Dh = 64, ENC = 128, SV = 1536;
    constexpr int SS_CUM[9] = {0,288,544,768,960,1120,1264,1392,1504};
    constexpr int SEQL[8] = {1152,1008,864,720,640,560,480,400};
    constexpr int QTN[8]  = {18,16,14,12,10,9,8,7};
    constexpr int OB[8]   = {2080,4096,3232,5104,0,1120,640,1680};
    constexpr int BB[8]   = {1,5,3,7,0,4,2,6};
    constexpr int ISUM[8] = {512,512,512,512,0,0,0,0};

    __shared__ __align__(16) short smem[2*64*KS];   // kbuf | vbuf ; reused as f32 tbuf in epilogue
    short* kbuf = smem;            // K[key][d] bf16
    short* vbuf = smem + 64*KS;    // V^T[d][key] bf16

    const int bid = blockIdx.x;
    int ss = 0;
    #pragma unroll
    for (int i = 1; i < 8; ++i) ss += (bid >= SS_CUM[i]) ? 1 : 0;
    const int seqlen   = SEQL[ss];
    const int nqt      = QTN[ss];
    const int b        = BB[ss];
    const int isum     = ISUM[ss];
    const int out_base = OB[ss];
    const int local    = bid - SS_CUM[ss];
    const int head     = local / nqt;
    const int qt       = local - head * nqt;

    const int tid  = threadIdx.x;
    const int wave = tid >> 6;
    const int lane = tid & 63;
    const int quad = lane >> 4;
    const int l15  = lane & 15;

    const float qmul = scale_p[0] * LOG2E;

    // ---- Q fragments (B-operand layout == A layout: n=l15, k=quad*8+j) ----
    const int qrow = qt*64 + wave*16 + l15;
    const float* qrp;
    if (qrow < ENC) qrp = eq + ((b*ENC + qrow)*H + head)*Dh;
    else            qrp = qv + (((b*SV + isum) + (qrow - ENC))*H + head)*Dh;
    bf16x8 qfrag[2];
    #pragma unroll
    for (int f = 0; f < 2; ++f) {
        const float* p = qrp + f*32 + quad*8;
        float4 a = *reinterpret_cast<const float4*>(p);
        float4 c = *reinterpret_cast<const float4*>(p + 4);
        uint4v u;
        u[0] = pack2bf(a.x*qmul, a.y*qmul);
        u[1] = pack2bf(a.z*qmul, a.w*qmul);
        u[2] = pack2bf(c.x*qmul, c.y*qmul);
        u[3] = pack2bf(c.z*qmul, c.w*qmul);
        qfrag[f] = __builtin_bit_cast(bf16x8, u);
    }

    f32x4 acc[4];                    // O^T: acc[dt] row d = dt*16+quad*4+reg, col q=l15
    #pragma unroll
    for (int dt = 0; dt < 4; ++dt) acc[dt] = {0.f,0.f,0.f,0.f};
    float m_s = -INFINITY, l_s = 0.f;   // per-lane scalars (q = l15)

    const int key_local = tid >> 2;      // 0..63
    const int dbase     = (tid & 3) * 16;
    const int nkt = (seqlen + 63) >> 6;
    const int src_base = l15 + ((quad & 1) << 5);   // bpermute source base lane

    for (int kt = 0; kt < nkt; ++kt) {
        if (kt) __syncthreads();
        {   // ---- stage 64 keys: fp32 -> bf16, K row-major, V transposed ----
            const int kr = kt*64 + key_local;
            const float *krow, *vrow;
            if (kr < ENC) {
                krow = ek + ((b*ENC + kr)*H + head)*Dh;
                vrow = ev + ((b*ENC + kr)*H + head)*Dh;
            } else {
                const int row = (b*SV + isum) + (kr - ENC);
                krow = kv + (row*H + head)*Dh;
                vrow = vv + (row*H + head)*Dh;
            }
            float4 kf[4], vf[4];
            #pragma unroll
            for (int j = 0; j < 4; ++j) {
                kf[j] = *reinterpret_cast<const float4*>(krow + dbase + 4*j);
                vf[j] = *reinterpret_cast<const float4*>(vrow + dbase + 4*j);
            }
            uint4v kp;
            kp[0] = pack2bf(kf[0].x, kf[0].y);
            kp[1] = pack2bf(kf[0].z, kf[0].w);
            kp[2] = pack2bf(kf[1].x, kf[1].y);
            kp[3] = pack2bf(kf[1].z, kf[1].w);
            *reinterpret_cast<uint4v*>(&kbuf[key_local*KS + dbase]) = kp;
            kp[0] = pack2bf(kf[2].x, kf[2].y);
            kp[1] = pack2bf(kf[2].z, kf[2].w);
            kp[2] = pack2bf(kf[3].x, kf[3].y);
            kp[3] = pack2bf(kf[3].z, kf[3].w);
            *reinterpret_cast<uint4v*>(&kbuf[key_local*KS + dbase + 8]) = kp;
            #pragma unroll
            for (int j = 0; j < 4; ++j) {
                float e[4] = {vf[j].x, vf[j].y, vf[j].z, vf[j].w};
                #pragma unroll
                for (int i = 0; i < 4; ++i) {
                    unsigned u = __builtin_bit_cast(unsigned, e[i]) + 0x8000u;
                    vbuf[(dbase + 4*j + i)*KS + key_local] = (short)(u >> 16);
                }
            }
        }
        __syncthreads();

        const int rem  = seqlen - kt*64;
        const int nsub = (rem >= 64) ? 4 : (rem >> 4);   // seqlens are multiples of 16

        // ---- QK^T -> S^T: lane holds keys sub*16+quad*4+r for q=l15 ----
        float s[4][4];
        #pragma unroll
        for (int sub = 0; sub < 4; ++sub) {
            if (sub < nsub) {
                const short* kr0 = &kbuf[(sub*16 + l15)*KS + quad*8];
                f32x4 sv = {0.f,0.f,0.f,0.f};
                sv = __builtin_amdgcn_mfma_f32_16x16x32_bf16(ldfrag(kr0),      qfrag[0], sv, 0,0,0);
                sv = __builtin_amdgcn_mfma_f32_16x16x32_bf16(ldfrag(kr0 + 32), qfrag[1], sv, 0,0,0);
                #pragma unroll
                for (int r = 0; r < 4; ++r) s[sub][r] = sv[r];
            } else {
                #pragma unroll
                for (int r = 0; r < 4; ++r) s[sub][r] = -INFINITY;
            }
        }

        // ---- online softmax (per-lane scalar state) ----
        float mx = s[0][0];
        #pragma unroll
        for (int sub = 0; sub < 4; ++sub)
            #pragma unroll
            for (int r = 0; r < 4; ++r) mx = fmaxf(mx, s[sub][r]);
        mx = fmaxf(mx, __shfl_xor(mx, 16, 64));
        mx = fmaxf(mx, __shfl_xor(mx, 32, 64));
        const float mn = fmaxf(m_s, mx);
        const float alpha = __builtin_amdgcn_exp2f(m_s - mn);
        m_s = mn;
        #pragma unroll
        for (int dt = 0; dt < 4; ++dt)
            #pragma unroll
            for (int r = 0; r < 4; ++r) acc[dt][r] *= alpha;

        float rs = 0.f;
        unsigned pk[4][2];
        #pragma unroll
        for (int sub = 0; sub < 4; ++sub) {
            float p0 = __builtin_amdgcn_exp2f(s[sub][0] - mn);
            float p1 = __builtin_amdgcn_exp2f(s[sub][1] - mn);
            float p2 = __builtin_amdgcn_exp2f(s[sub][2] - mn);
            float p3 = __builtin_amdgcn_exp2f(s[sub][3] - mn);
            rs += (p0 + p1) + (p2 + p3);
            pk[sub][0] = pack2bf(p0, p1);
            pk[sub][1] = pack2bf(p2, p3);
        }
        rs += __shfl_xor(rs, 16, 64);
        rs += __shfl_xor(rs, 32, 64);
        l_s = l_s * alpha + rs;

        // ---- PV: O^T += V^T x P^T ; P^T B-frag via bpermute ----
        #pragma unroll
        for (int kstep = 0; kstep < 2; ++kstep) {
            if (kstep == 0 || nsub > 2) {
                uint4v pf;
                #pragma unroll
                for (int p = 0; p < 4; ++p) {
                    const int sl = src_base + ((p >> 1) << 4);
                    int va = __shfl((int)pk[kstep*2 + 0][p & 1], sl, 64);
                    int vb = __shfl((int)pk[kstep*2 + 1][p & 1], sl, 64);
                    pf[p] = (quad & 2) ? (unsigned)vb : (unsigned)va;
                }
                bf16x8 pfr = __builtin_bit_cast(bf16x8, pf);
                #pragma unroll
                for (int dt = 0; dt < 4; ++dt) {
                    bf16x8 vfr = ldfrag(&vbuf[(dt*16 + l15)*KS + kstep*32 + quad*8]);
                    acc[dt] = __builtin_amdgcn_mfma_f32_16x16x32_bf16(vfr, pfr, acc[dt], 0,0,0);
                }
            }
        }
    }

    // ---- epilogue: normalize, transpose via LDS, coalesced f32 store ----
    __syncthreads();                       // all waves done reading kbuf/vbuf
    float* tbuf = reinterpret_cast<float*>(smem);   // [64][68] f32 = 17408 B
    const float inv = 1.0f / l_s;
    #pragma unroll
    for (int dt = 0; dt < 4; ++dt)
        #pragma unroll
        for (int r = 0; r < 4; ++r)
            tbuf[(wave*16 + l15)*68 + dt*16 + quad*4 + r] = acc[dt][r] * inv;
    __syncthreads();

    const int rowl = tid >> 2;
    const int grow = qt*64 + rowl;
    if (grow < seqlen) {
        float* orow = out + (size_t)(out_base + grow)*(H*Dh) + head*Dh;
        const float* trow = tbuf + rowl*68 + (tid & 3)*4;
        #pragma unroll
        for (int c = 0; c < 4; ++c)
            *reinterpret_cast<float4*>(orow + (tid & 3)*4 + c*16) =
                *reinterpret_cast<const float4*>(trow + c*16);
    }
}

extern "C" void kernel_launch(void* const* d_in, const int* in_sizes, int n_in,
                              void* d_out, int out_size, void* d_ws, size_t ws_size,
                              hipStream_t stream) {
    const float* q     = (const float*)d_in[0];
    const float* k     = (const float*)d_in[1];
    const float* v     = (const float*)d_in[2];
    const float* eq    = (const float*)d_in[3];
    const float* ek    = (const float*)d_in[4];
    const float* ev    = (const float*)d_in[5];
    const float* scale = (const float*)d_in[11];
    float* out = (float*)d_out;

    vfa_kernel<<<dim3(1504), dim3(256), 0, stream>>>(q, k, v, eq, ek, ev, scale, out);
}